// Round 1
// baseline (4145.098 us; speedup 1.0000x reference)
//
#include <hip/hip_runtime.h>
#include <math.h>

#define B_    4
#define CIN_  256
#define COUT_ 256
#define H_    128
#define W_    128
#define SD_   512
#define HO_   130      // conv output spatial (128 + 2*2 - 3 + 1)
#define HU_   260      // upsampled spatial
#define NT_   12

// ---------------- K1: modulation s[b][cin] ----------------
__global__ __launch_bounds__(256) void k_mod(const float* __restrict__ style,
                                             const float* __restrict__ mw,
                                             const float* __restrict__ mb,
                                             float* __restrict__ s) {
  int wid  = (blockIdx.x * blockDim.x + threadIdx.x) >> 6;   // 0..1023
  int lane = threadIdx.x & 63;
  int b = wid >> 8, ci = wid & 255;
  const float* st = style + b * SD_;
  const float* w  = mw + ci * SD_;
  float acc = 0.f;
  for (int k = lane; k < SD_; k += 64) acc += st[k] * w[k];
  for (int off = 32; off; off >>= 1) acc += __shfl_down(acc, off);
  if (lane == 0) s[wid] = acc * 0.044194173824159216f + mb[ci];  // 1/sqrt(512)
}

// ---------------- K2: demod[b][cout] ----------------
__global__ __launch_bounds__(256) void k_demod(const float* __restrict__ weight,
                                               const float* __restrict__ s,
                                               float* __restrict__ demod) {
  int wid  = (blockIdx.x * blockDim.x + threadIdx.x) >> 6;   // 0..1023
  int lane = threadIdx.x & 63;
  int b = wid >> 8, co = wid & 255;
  const float* wrow = weight + co * CIN_ * 9;
  const float* sb   = s + b * CIN_;
  float acc = 0.f;
  for (int e = lane; e < CIN_ * 9; e += 64) {
    float p = wrow[e] * sb[e / 9];
    acc += p * p;
  }
  for (int off = 32; off; off >>= 1) acc += __shfl_down(acc, off);
  if (lane == 0) demod[wid] = rsqrtf(acc + 1e-8f);
}

// ---------------- K3: modulated conv (fp32, register-blocked) ----------------
#define PY  8
#define PX  16
#define COT 64
#define CIT 4

__global__ __launch_bounds__(256) void k_conv(const float* __restrict__ input,
                                              const float* __restrict__ weight,
                                              const float* __restrict__ s,
                                              const float* __restrict__ demod,
                                              const float* __restrict__ bias,
                                              float* __restrict__ out1) {
  // grid: x = col tiles (9), y = row tiles (17), z = b*4 + co_group
  int x0  = blockIdx.x * PX;
  int y0  = blockIdx.y * PY;
  int b   = blockIdx.z >> 2;
  int co0 = (blockIdx.z & 3) * COT;
  int tid = threadIdx.x;

  __shared__ float xs[CIT][10][19];                 // input patch, stride 19
  __shared__ __align__(16) float wl[CIT][COT][12];  // 9 taps padded to 12 (48B)

  int tc = tid >> 5;        // 0..7 : co sub-group
  int p  = tid & 31;        // pixel group
  int pr = p >> 2;          // 0..7 : tile row
  int pc = (p & 3) * 4;     // 0,4,8,12 : tile col base

  float acc[8][4];
#pragma unroll
  for (int j = 0; j < 8; ++j)
#pragma unroll
    for (int q = 0; q < 4; ++q) acc[j][q] = 0.f;

  const float* sb = s + b * CIN_;

  for (int c0 = 0; c0 < CIN_; c0 += CIT) {
    __syncthreads();
    // stage input: CIT x 10 x 18 = 720 elements (modulated by s)
    for (int idx = tid; idx < CIT * 10 * 18; idx += 256) {
      int ci = idx / 180, rem = idx % 180;
      int r = rem / 18, c = rem % 18;
      int iy = y0 - 2 + r, ix = x0 - 2 + c;
      float v = 0.f;
      if (iy >= 0 && iy < H_ && ix >= 0 && ix < W_)
        v = input[((b * CIN_ + c0 + ci) * H_ + iy) * W_ + ix] * sb[c0 + ci];
      xs[ci][r][c] = v;
    }
    // stage weights: CIT x 64 x 9 = 2304 elements
    for (int idx = tid; idx < CIT * COT * 9; idx += 256) {
      int ci = idx / (COT * 9), rem = idx % (COT * 9);
      int co = rem / 9, k = rem % 9;
      wl[ci][co][k] = weight[((co0 + co) * CIN_ + c0 + ci) * 9 + k];
    }
    __syncthreads();

#pragma unroll
    for (int ci = 0; ci < CIT; ++ci) {
      float xin[3][6];
#pragma unroll
      for (int r = 0; r < 3; ++r)
#pragma unroll
        for (int c = 0; c < 6; ++c) xin[r][c] = xs[ci][pr + r][pc + c];

#pragma unroll
      for (int j = 0; j < 8; ++j) {
        int co = tc * 8 + j;
        const float4* wv = (const float4*)&wl[ci][co][0];
        float4 wa = wv[0];
        float4 wb = wv[1];
        float  w8 = wl[ci][co][8];
#pragma unroll
        for (int q = 0; q < 4; ++q) {
          float a = acc[j][q];
          a += wa.x * xin[0][q]     + wa.y * xin[0][q + 1] + wa.z * xin[0][q + 2];
          a += wa.w * xin[1][q]     + wb.x * xin[1][q + 1] + wb.y * xin[1][q + 2];
          a += wb.z * xin[2][q]     + wb.w * xin[2][q + 1] + w8  * xin[2][q + 2];
          acc[j][q] = a;
        }
      }
    }
  }

  // epilogue: * demod + bias
#pragma unroll
  for (int j = 0; j < 8; ++j) {
    int co = co0 + tc * 8 + j;
    float d  = demod[b * COUT_ + co];
    float bv = bias[co];
    int oy = y0 + pr;
    if (oy < HO_) {
#pragma unroll
      for (int q = 0; q < 4; ++q) {
        int ox = x0 + pc + q;
        if (ox < HO_)
          out1[(((size_t)b * COUT_ + co) * HO_ + oy) * HO_ + ox] = acc[j][q] * d + bv;
      }
    }
  }
}

// ---------------- K4: fused FIR up(2x) -> lrelu -> FIR down(2x) ----------------
// tile = 26x26 output pixels (5x5 tiles cover 130 exactly)
#define TS 26
#define XR 36   // staged src extent: y0-5 .. y0+30
#define UR 62   // intermediate (260-grid) extent: 2*y0-5 .. 2*y0+56

__global__ __launch_bounds__(256) void k_fir(const float* __restrict__ src,
                                             const float* __restrict__ upf,
                                             const float* __restrict__ dnf,
                                             float* __restrict__ dst) {
  int plane = blockIdx.z;                 // b*256 + co
  int y0 = blockIdx.y * TS, x0 = blockIdx.x * TS;
  int tid = threadIdx.x;

  __shared__ float buf1[UR * 63];         // X (stride 37) then I2 (stride 63)
  __shared__ float buf2[UR * 37];         // I1 (stride 37) then D1 (stride 63)
  __shared__ float fu[NT_], fd[NT_];
  if (tid < NT_) { fu[tid] = upf[tid] * 2.f; fd[tid] = dnf[tid]; }

  // stage A: load src tile (zero outside [0,130)^2)
  const float* sp = src + (size_t)plane * HO_ * HO_;
  for (int idx = tid; idx < XR * XR; idx += 256) {
    int r = idx / XR, c = idx % XR;
    int gy = y0 - 5 + r, gx = x0 - 5 + c;
    float v = 0.f;
    if (gy >= 0 && gy < HO_ && gx >= 0 && gx < HO_) v = sp[gy * HO_ + gx];
    buf1[r * 37 + c] = v;
  }
  __syncthreads();

  // stage B: vertical up-FIR  I1[u][c]
  for (int idx = tid; idx < UR * XR; idx += 256) {
    int u = idx / XR, c = idx % XR;
    int ug = 2 * y0 - 5 + u;
    float a = 0.f;
    if (ug >= 0 && ug < HU_) {
      int base, toff;
      if (ug & 1) { base = (ug - 5) >> 1; toff = 1; }
      else        { base = (ug >> 1) - 3; toff = 0; }
      int lr = base - (y0 - 5);
#pragma unroll
      for (int j = 0; j < 6; ++j) a += fu[2 * j + toff] * buf1[(lr + j) * 37 + c];
    }
    buf2[u * 37 + c] = a;
  }
  __syncthreads();

  // stage C: horizontal up-FIR + lrelu*sqrt(2) + clamp  I2[u][v]
  for (int idx = tid; idx < UR * UR; idx += 256) {
    int u = idx / UR, v = idx % UR;
    int ug = 2 * y0 - 5 + u;
    int vg = 2 * x0 - 5 + v;
    float a = 0.f;
    if (ug >= 0 && ug < HU_ && vg >= 0 && vg < HU_) {
      int base, toff;
      if (vg & 1) { base = (vg - 5) >> 1; toff = 1; }
      else        { base = (vg >> 1) - 3; toff = 0; }
      int lc = base - (x0 - 5);
#pragma unroll
      for (int j = 0; j < 6; ++j) a += fu[2 * j + toff] * buf2[u * 37 + lc + j];
      a = (a >= 0.f ? a : 0.2f * a) * 1.41421356237309515f;
      a = fminf(fmaxf(a, -256.f), 256.f);
    }
    buf1[u * 63 + v] = a;
  }
  __syncthreads();

  // stage D: vertical down-FIR  D1[y][v]
  for (int idx = tid; idx < TS * UR; idx += 256) {
    int y = idx / UR, v = idx % UR;
    float a = 0.f;
#pragma unroll
    for (int t = 0; t < NT_; ++t) a += fd[t] * buf1[(2 * y + t) * 63 + v];
    buf2[y * 63 + v] = a;
  }
  __syncthreads();

  // stage E: horizontal down-FIR -> out
  float* dp = dst + (size_t)plane * HO_ * HO_;
  for (int idx = tid; idx < TS * TS; idx += 256) {
    int y = idx / TS, x = idx % TS;
    float a = 0.f;
#pragma unroll
    for (int t = 0; t < NT_; ++t) a += fd[t] * buf2[y * 63 + 2 * x + t];
    dp[(y0 + y) * HO_ + (x0 + x)] = a;
  }
}

// ---------------- launch ----------------
extern "C" void kernel_launch(void* const* d_in, const int* in_sizes, int n_in,
                              void* d_out, int out_size, void* d_ws, size_t ws_size,
                              hipStream_t stream) {
  (void)in_sizes; (void)n_in; (void)out_size; (void)ws_size;
  const float* input  = (const float*)d_in[0];
  const float* style  = (const float*)d_in[1];
  const float* weight = (const float*)d_in[2];
  const float* mw     = (const float*)d_in[3];
  const float* mb     = (const float*)d_in[4];
  const float* bias   = (const float*)d_in[5];
  const float* upf    = (const float*)d_in[6];
  const float* dnf    = (const float*)d_in[7];
  float* out  = (float*)d_out;

  float* out1  = (float*)d_ws;                               // [4][256][130][130]
  float* s     = out1 + (size_t)B_ * COUT_ * HO_ * HO_;      // [4][256]
  float* demod = s + B_ * CIN_;                              // [4][256]

  k_mod  <<<256, 256, 0, stream>>>(style, mw, mb, s);
  k_demod<<<256, 256, 0, stream>>>(weight, s, demod);
  k_conv <<<dim3((HO_ + PX - 1) / PX, (HO_ + PY - 1) / PY, B_ * 4), 256, 0, stream>>>(
      input, weight, s, demod, bias, out1);
  k_fir  <<<dim3(5, 5, B_ * COUT_), 256, 0, stream>>>(out1, upf, dnf, out);
}

// Round 2
// 649.956 us; speedup vs baseline: 6.3775x; 6.3775x over previous
//
#include <hip/hip_runtime.h>
#include <math.h>

#define B_    4
#define CIN_  256
#define COUT_ 256
#define H_    128
#define W_    128
#define SD_   512
#define HO_   130
#define HU_   260
#define NT_   12

typedef unsigned short ushort_t;
typedef __attribute__((ext_vector_type(8))) short short8;
typedef __attribute__((ext_vector_type(4))) float f32x4;

__device__ inline ushort_t f2bf_(float v) {
  union { float f; unsigned u; } x; x.f = v;
  unsigned r = x.u + 0x7fffu + ((x.u >> 16) & 1u);
  return (ushort_t)(r >> 16);
}
__device__ inline float bf2f_(ushort_t h) {
  union { unsigned u; float f; } x; x.u = ((unsigned)h) << 16;
  return x.f;
}
__device__ inline void gll16(const ushort_t* g, ushort_t* l) {
  __builtin_amdgcn_global_load_lds(
      (const __attribute__((address_space(1))) unsigned int*)g,
      (__attribute__((address_space(3))) unsigned int*)l, 16, 0, 0);
}

// ---------------- K1: modulation s[b][cin] ----------------
__global__ __launch_bounds__(256) void k_mod(const float* __restrict__ style,
                                             const float* __restrict__ mw,
                                             const float* __restrict__ mb,
                                             float* __restrict__ s) {
  int wid  = (blockIdx.x * blockDim.x + threadIdx.x) >> 6;
  int lane = threadIdx.x & 63;
  int b = wid >> 8, ci = wid & 255;
  const float* st = style + b * SD_;
  const float* w  = mw + ci * SD_;
  float acc = 0.f;
  for (int k = lane; k < SD_; k += 64) acc += st[k] * w[k];
  for (int off = 32; off; off >>= 1) acc += __shfl_down(acc, off);
  if (lane == 0) s[wid] = acc * 0.044194173824159216f + mb[ci];
}

// ---------------- K2: demod[b][cout] ----------------
__global__ __launch_bounds__(256) void k_demod(const float* __restrict__ weight,
                                               const float* __restrict__ s,
                                               float* __restrict__ demod) {
  int wid  = (blockIdx.x * blockDim.x + threadIdx.x) >> 6;
  int lane = threadIdx.x & 63;
  int b = wid >> 8, co = wid & 255;
  const float* wrow = weight + co * CIN_ * 9;
  const float* sb   = s + b * CIN_;
  float acc = 0.f;
  for (int e = lane; e < CIN_ * 9; e += 64) {
    float p = wrow[e] * sb[e / 9];
    acc += p * p;
  }
  for (int off = 32; off; off >>= 1) acc += __shfl_down(acc, off);
  if (lane == 0) demod[wid] = rsqrtf(acc + 1e-8f);
}

// ---------------- K2b: weight pre-transform to MFMA-ready layout ----------------
// dst layout: [tap(9)][cb(2)][kb(8)][kc(4)][co(128)][j(8)]  (bf16 hi / lo arrays)
__global__ __launch_bounds__(256) void k_prep_w(const float* __restrict__ W,
                                                ushort_t* __restrict__ Wth,
                                                ushort_t* __restrict__ Wtl) {
  int idx = blockIdx.x * 256 + threadIdx.x;
  if (idx >= 589824) return;
  int j  = idx & 7;
  int co = (idx >> 3) & 127;
  int kc = (idx >> 10) & 3;
  int kb = (idx >> 12) & 7;
  int cb = (idx >> 15) & 1;
  int t  = idx >> 16;
  int ci  = kb * 32 + kc * 8 + j;
  int cog = cb * 128 + co;
  float v = W[(cog * CIN_ + ci) * 9 + t];
  ushort_t h = f2bf_(v);
  Wth[idx] = h;
  Wtl[idx] = f2bf_(v - bf2f_(h));
}

// ---------------- K3: modulated conv via MFMA (bf16 split-3) ----------------
// block tile: 128 co x (8y x 16x) px, K staged 32 ci at a time, 9 taps
__global__ __launch_bounds__(256, 2) void k_conv_mfma(
    const float* __restrict__ input, const ushort_t* __restrict__ Wth,
    const ushort_t* __restrict__ Wtl, const float* __restrict__ s,
    const float* __restrict__ demod, const float* __restrict__ bias,
    float* __restrict__ out1) {
  const int tid = threadIdx.x;
  const int b   = blockIdx.z >> 1, cb = blockIdx.z & 1;
  const int co0 = cb * 128;
  const int y0  = blockIdx.y * 8, x0 = blockIdx.x * 16;
  const int lane = tid & 63, lr = lane & 15, kcc = lane >> 4;
  const int w = tid >> 6, wm = w >> 1, wn = w & 1;

  // X: [kc(4)][hy(10)][hx(18)][j(8)]  bf16 -> 16B contiguous per (hy,hx)
  __shared__ __align__(16) ushort_t XhL[5760], XlL[5760];
  // W: [buf(2)][kc(4)][co(128)][j(8)]
  __shared__ __align__(16) ushort_t WhL[2][4096], WlL[2][4096];
  __shared__ float sSh[256];

  f32x4 acc[4][4];
#pragma unroll
  for (int i = 0; i < 4; ++i)
#pragma unroll
    for (int jq = 0; jq < 4; ++jq) acc[i][jq] = (f32x4)0.f;

  sSh[tid] = s[b * 256 + tid];

  auto stage_w = [&](int t, int kbb, int buf) {
    const ushort_t* sh = Wth + ((((t * 2 + cb) * 8) + kbb) << 12);
    const ushort_t* sl = Wtl + ((((t * 2 + cb) * 8) + kbb) << 12);
    int o0 = tid * 8, o1 = 2048 + tid * 8;   // ushort offsets (16B per thread)
    gll16(sh + o0, &WhL[buf][o0]);
    gll16(sh + o1, &WhL[buf][o1]);
    gll16(sl + o0, &WlL[buf][o0]);
    gll16(sl + o1, &WlL[buf][o1]);
  };

  auto stage_x = [&](int kbb) {
    const float* inb = input + (b * 256 + kbb * 32) * (H_ * W_);
    for (int idx = tid; idx < 5760; idx += 256) {
      int ci  = idx / 180;
      int rem = idx - ci * 180;
      int hy  = rem / 18;
      int hx  = rem - hy * 18;
      int iy = y0 + hy - 2, ix = x0 + hx - 2;
      float v = 0.f;
      if ((unsigned)iy < (unsigned)H_ && (unsigned)ix < (unsigned)W_)
        v = inb[ci * (H_ * W_) + iy * W_ + ix];
      v *= sSh[kbb * 32 + ci];
      ushort_t h = f2bf_(v);
      ushort_t lo = f2bf_(v - bf2f_(h));
      int off = ((ci >> 3) * 180 + rem) * 8 + (ci & 7);
      XhL[off] = h;
      XlL[off] = lo;
    }
  };

  auto mfma_step = [&](int tp, int buf) {
    int ky = tp / 3;
    int kx = tp - 3 * ky;
    short8 ah[4], al[4], bh4[4], bl4[4];
#pragma unroll
    for (int am = 0; am < 4; ++am) {
      int off = kcc * 1024 + (wm * 64 + am * 16 + lr) * 8;
      ah[am] = *(const short8*)&WhL[buf][off];
      al[am] = *(const short8*)&WlL[buf][off];
    }
#pragma unroll
    for (int bn = 0; bn < 4; ++bn) {
      int hy = wn * 4 + bn + ky, hx = lr + kx;
      int off = kcc * 1440 + (hy * 18 + hx) * 8;
      bh4[bn] = *(const short8*)&XhL[off];
      bl4[bn] = *(const short8*)&XlL[off];
    }
#pragma unroll
    for (int am = 0; am < 4; ++am)
#pragma unroll
      for (int bn = 0; bn < 4; ++bn) {
        acc[am][bn] = __builtin_amdgcn_mfma_f32_16x16x32_bf16(ah[am], bh4[bn], acc[am][bn], 0, 0, 0);
        acc[am][bn] = __builtin_amdgcn_mfma_f32_16x16x32_bf16(ah[am], bl4[bn], acc[am][bn], 0, 0, 0);
        acc[am][bn] = __builtin_amdgcn_mfma_f32_16x16x32_bf16(al[am], bh4[bn], acc[am][bn], 0, 0, 0);
      }
  };

  stage_w(0, 0, 0);     // async prefetch, drained at first barrier
  __syncthreads();      // sSh visible
  stage_x(0);
  __syncthreads();      // X visible, W0 visible

  int tap = 0, kb = 0, cur = 0;
  for (int u = 0; u < 72; ++u) {
    int ntap = (tap == 8) ? 0 : tap + 1;
    int nkb  = (tap == 8) ? kb + 1 : kb;
    if (u < 71) stage_w(ntap, nkb, cur ^ 1);   // async, overlaps MFMA below
    mfma_step(tap, cur);
    if (u < 71) {
      if (ntap == 0) {
        __syncthreads();      // all waves done reading X(kb)
        stage_x(nkb);
      }
      __syncthreads();        // new W (and X) visible
      cur ^= 1;
    }
    tap = ntap; kb = nkb;
  }

  // epilogue: * demod + bias, bounded store
#pragma unroll
  for (int am = 0; am < 4; ++am) {
#pragma unroll
    for (int r = 0; r < 4; ++r) {
      int cog = co0 + wm * 64 + am * 16 + kcc * 4 + r;
      float dm = demod[b * 256 + cog];
      float bv = bias[cog];
#pragma unroll
      for (int bn = 0; bn < 4; ++bn) {
        int oy = y0 + wn * 4 + bn;
        int ox = x0 + lr;
        if (oy < HO_ && ox < HO_)
          out1[((b * 256 + cog) * HO_ + oy) * HO_ + ox] = acc[am][bn][r] * dm + bv;
      }
    }
  }
}

// ---------------- K4: fused FIR up(2x) -> lrelu -> FIR down(2x) ----------------
#define TS 26
#define XR 36
#define UR 62

__global__ __launch_bounds__(256) void k_fir(const float* __restrict__ src,
                                             const float* __restrict__ upf,
                                             const float* __restrict__ dnf,
                                             float* __restrict__ dst) {
  int plane = blockIdx.z;
  int y0 = blockIdx.y * TS, x0 = blockIdx.x * TS;
  int tid = threadIdx.x;

  __shared__ float buf1[UR * 63];
  __shared__ float buf2[UR * 37];
  __shared__ float fu[NT_], fd[NT_];
  if (tid < NT_) { fu[tid] = upf[tid] * 2.f; fd[tid] = dnf[tid]; }

  const float* sp = src + (size_t)plane * HO_ * HO_;
  for (int idx = tid; idx < XR * XR; idx += 256) {
    int r = idx / XR, c = idx % XR;
    int gy = y0 - 5 + r, gx = x0 - 5 + c;
    float v = 0.f;
    if (gy >= 0 && gy < HO_ && gx >= 0 && gx < HO_) v = sp[gy * HO_ + gx];
    buf1[r * 37 + c] = v;
  }
  __syncthreads();

  for (int idx = tid; idx < UR * XR; idx += 256) {
    int u = idx / XR, c = idx % XR;
    int ug = 2 * y0 - 5 + u;
    float a = 0.f;
    if (ug >= 0 && ug < HU_) {
      int base, toff;
      if (ug & 1) { base = (ug - 5) >> 1; toff = 1; }
      else        { base = (ug >> 1) - 3; toff = 0; }
      int lr2 = base - (y0 - 5);
#pragma unroll
      for (int j = 0; j < 6; ++j) a += fu[2 * j + toff] * buf1[(lr2 + j) * 37 + c];
    }
    buf2[u * 37 + c] = a;
  }
  __syncthreads();

  for (int idx = tid; idx < UR * UR; idx += 256) {
    int u = idx / UR, v = idx % UR;
    int ug = 2 * y0 - 5 + u;
    int vg = 2 * x0 - 5 + v;
    float a = 0.f;
    if (ug >= 0 && ug < HU_ && vg >= 0 && vg < HU_) {
      int base, toff;
      if (vg & 1) { base = (vg - 5) >> 1; toff = 1; }
      else        { base = (vg >> 1) - 3; toff = 0; }
      int lc = base - (x0 - 5);
#pragma unroll
      for (int j = 0; j < 6; ++j) a += fu[2 * j + toff] * buf2[u * 37 + lc + j];
      a = (a >= 0.f ? a : 0.2f * a) * 1.41421356237309515f;
      a = fminf(fmaxf(a, -256.f), 256.f);
    }
    buf1[u * 63 + v] = a;
  }
  __syncthreads();

  for (int idx = tid; idx < TS * UR; idx += 256) {
    int y = idx / UR, v = idx % UR;
    float a = 0.f;
#pragma unroll
    for (int t = 0; t < NT_; ++t) a += fd[t] * buf1[(2 * y + t) * 63 + v];
    buf2[y * 63 + v] = a;
  }
  __syncthreads();

  float* dp = dst + (size_t)plane * HO_ * HO_;
  for (int idx = tid; idx < TS * TS; idx += 256) {
    int y = idx / TS, x = idx % TS;
    float a = 0.f;
#pragma unroll
    for (int t = 0; t < NT_; ++t) a += fd[t] * buf2[y * 63 + 2 * x + t];
    dp[(y0 + y) * HO_ + (x0 + x)] = a;
  }
}

// ---------------- launch ----------------
extern "C" void kernel_launch(void* const* d_in, const int* in_sizes, int n_in,
                              void* d_out, int out_size, void* d_ws, size_t ws_size,
                              hipStream_t stream) {
  (void)in_sizes; (void)n_in; (void)out_size; (void)ws_size;
  const float* input  = (const float*)d_in[0];
  const float* style  = (const float*)d_in[1];
  const float* weight = (const float*)d_in[2];
  const float* mw     = (const float*)d_in[3];
  const float* mb     = (const float*)d_in[4];
  const float* bias   = (const float*)d_in[5];
  const float* upf    = (const float*)d_in[6];
  const float* dnf    = (const float*)d_in[7];
  float* out = (float*)d_out;

  float* out1   = (float*)d_ws;                               // [4][256][130][130]
  float* s      = out1 + (size_t)B_ * COUT_ * HO_ * HO_;      // [4][256]
  float* demod  = s + B_ * CIN_;                              // [4][256]
  ushort_t* Wth = (ushort_t*)(demod + B_ * COUT_);            // 589824
  ushort_t* Wtl = Wth + 589824;                               // 589824

  k_mod   <<<256, 256, 0, stream>>>(style, mw, mb, s);
  k_demod <<<256, 256, 0, stream>>>(weight, s, demod);
  k_prep_w<<<2304, 256, 0, stream>>>(weight, Wth, Wtl);
  k_conv_mfma<<<dim3(9, 17, 8), 256, 0, stream>>>(input, Wth, Wtl, s, demod, bias, out1);
  k_fir   <<<dim3(5, 5, B_ * COUT_), 256, 0, stream>>>(out1, upf, dnf, out);
}

// Round 3
// 528.929 us; speedup vs baseline: 7.8368x; 1.2288x over previous
//
#include <hip/hip_runtime.h>
#include <hip/hip_bf16.h>
#include <math.h>

#define B_    4
#define CIN_  256
#define COUT_ 256
#define H_    128
#define W_    128
#define SD_   512
#define HO_   130
#define HU_   260
#define NT_   12

typedef unsigned short ushort_t;
typedef __attribute__((ext_vector_type(8))) short short8;
typedef __attribute__((ext_vector_type(4))) short short4v;
typedef __attribute__((ext_vector_type(4))) float f32x4;

__device__ inline ushort_t f2bf_(float v) {
  union { float f; unsigned u; } x; x.f = v;
  unsigned r = x.u + 0x7fffu + ((x.u >> 16) & 1u);
  return (ushort_t)(r >> 16);
}
__device__ inline float bf2f_(ushort_t h) {
  union { unsigned u; float f; } x; x.u = ((unsigned)h) << 16;
  return x.f;
}

// ---------------- K1: modulation s[b][cin] ----------------
__global__ __launch_bounds__(256) void k_mod(const float* __restrict__ style,
                                             const float* __restrict__ mw,
                                             const float* __restrict__ mb,
                                             float* __restrict__ s) {
  int wid  = (blockIdx.x * blockDim.x + threadIdx.x) >> 6;
  int lane = threadIdx.x & 63;
  int b = wid >> 8, ci = wid & 255;
  const float* st = style + b * SD_;
  const float* w  = mw + ci * SD_;
  float acc = 0.f;
  for (int k = lane; k < SD_; k += 64) acc += st[k] * w[k];
  for (int off = 32; off; off >>= 1) acc += __shfl_down(acc, off);
  if (lane == 0) s[wid] = acc * 0.044194173824159216f + mb[ci];
}

// ---------------- K2: demod[b][cout] ----------------
__global__ __launch_bounds__(256) void k_demod(const float* __restrict__ weight,
                                               const float* __restrict__ s,
                                               float* __restrict__ demod) {
  int wid  = (blockIdx.x * blockDim.x + threadIdx.x) >> 6;
  int lane = threadIdx.x & 63;
  int b = wid >> 8, co = wid & 255;
  const float* wrow = weight + co * CIN_ * 9;
  const float* sb   = s + b * CIN_;
  float acc = 0.f;
  for (int e = lane; e < CIN_ * 9; e += 64) {
    float p = wrow[e] * sb[e / 9];
    acc += p * p;
  }
  for (int off = 32; off; off >>= 1) acc += __shfl_down(acc, off);
  if (lane == 0) demod[wid] = rsqrtf(acc + 1e-8f);
}

// ---------------- K2b: weight pre-transform to MFMA fragment layout ----------------
// layout: [tap(9)][cb(2)][kb(8)][kcc(4)][co_row(128)][j(8)]   (hi / lo arrays)
__global__ __launch_bounds__(256) void k_prep_w(const float* __restrict__ W,
                                                ushort_t* __restrict__ Wth,
                                                ushort_t* __restrict__ Wtl) {
  int idx = blockIdx.x * 256 + threadIdx.x;
  if (idx >= 589824) return;
  int j  = idx & 7;
  int co = (idx >> 3) & 127;
  int kc = (idx >> 10) & 3;
  int kb = (idx >> 12) & 7;
  int cb = (idx >> 15) & 1;
  int t  = idx >> 16;
  int ci  = kb * 32 + kc * 8 + j;
  int cog = cb * 128 + co;
  float v = W[(cog * CIN_ + ci) * 9 + t];
  ushort_t h = f2bf_(v);
  Wth[idx] = h;
  Wtl[idx] = f2bf_(v - bf2f_(h));
}

// ---------------- K3: modulated conv via MFMA (bf16 split-3) ----------------
// block tile: 128 co x (8y x 16x) px; W fragments loaded straight from L2;
// X staged in LDS (double-buffered, jq-split layout, conflict-free).
__global__ __launch_bounds__(256, 2) void k_conv_mfma(
    const float* __restrict__ input, const ushort_t* __restrict__ Wth,
    const ushort_t* __restrict__ Wtl, const float* __restrict__ s,
    const float* __restrict__ demod, const float* __restrict__ bias,
    float* __restrict__ out1) {
  const int tid = threadIdx.x;
  const int b   = blockIdx.z >> 1, cb = blockIdx.z & 1;
  const int co0 = cb * 128;
  const int y0  = blockIdx.y * 8, x0 = blockIdx.x * 16;
  const int lane = tid & 63, lr = lane & 15, kcc = lane >> 4;
  const int w = tid >> 6, wm = w >> 1, wn = w & 1;

  // X LDS: [buf(2)][jq(2)][cell(720)][4 ushorts]; cell = kc*180 + hy*18 + hx
  __shared__ __align__(16) ushort_t XhL[2][5760];
  __shared__ __align__(16) ushort_t XlL[2][5760];
  __shared__ float sSh[256];

  f32x4 acc[4][4];
#pragma unroll
  for (int i = 0; i < 4; ++i)
#pragma unroll
    for (int jj = 0; jj < 4; ++jj) acc[i][jj] = (f32x4)0.f;

  sSh[tid] = s[b * 256 + tid];
  const float* inb = input + b * 256 * (H_ * W_);

  // per-thread quad decode (6 quads of 4 ci-consecutive elements)
  int qjq[6], qcell[6], qkc[6], qiy[6], qix[6];
#pragma unroll
  for (int k2 = 0; k2 < 6; ++k2) {
    int q = tid + k2 * 256;
    int jq = (q >= 720) ? 1 : 0;
    int cell = q - jq * 720;
    int kc = cell / 180, rem = cell % 180;
    int hy = rem / 18, hx = rem % 18;
    qjq[k2] = jq; qcell[k2] = cell; qkc[k2] = kc;
    qiy[k2] = y0 + hy - 2; qix[k2] = x0 + hx - 2;
  }

  auto xload = [&](int kb, float (&xq)[6][4]) {
#pragma unroll
    for (int k2 = 0; k2 < 6; ++k2) {
      int q = tid + k2 * 256;
      if (q < 1440) {
        bool ok = (unsigned)qiy[k2] < (unsigned)H_ && (unsigned)qix[k2] < (unsigned)W_;
        const float* p = inb + (kb * 32 + qkc[k2] * 8 + qjq[k2] * 4) * (H_ * W_) +
                         qiy[k2] * W_ + qix[k2];
#pragma unroll
        for (int u2 = 0; u2 < 4; ++u2)
          xq[k2][u2] = ok ? p[u2 * (H_ * W_)] : 0.f;
      }
    }
  };
  auto xstore = [&](int kb, int buf, float (&xq)[6][4]) {
#pragma unroll
    for (int k2 = 0; k2 < 6; ++k2) {
      int q = tid + k2 * 256;
      if (q < 1440) {
        int sbase = kb * 32 + qkc[k2] * 8 + qjq[k2] * 4;
        ushort_t h[4], l[4];
#pragma unroll
        for (int u2 = 0; u2 < 4; ++u2) {
          float v = xq[k2][u2] * sSh[sbase + u2];
          ushort_t hh = f2bf_(v);
          h[u2] = hh;
          l[u2] = f2bf_(v - bf2f_(hh));
        }
        int off = qjq[k2] * 2880 + qcell[k2] * 4;
        *(short4v*)&XhL[buf][off] = (short4v){(short)h[0], (short)h[1], (short)h[2], (short)h[3]};
        *(short4v*)&XlL[buf][off] = (short4v){(short)l[0], (short)l[1], (short)l[2], (short)l[3]};
      }
    }
  };

  {
    float xq[6][4];
    xload(0, xq);
    __syncthreads();          // sSh visible
    xstore(0, 0, xq);
  }
  __syncthreads();

  int cur = 0;
  const int aoff = kcc * 1024 + (wm * 64 + lr) * 8;

  for (int kb = 0; kb < 8; ++kb) {
    float xn[6][4];
    if (kb < 7) xload(kb + 1, xn);   // issue early — hides HBM latency under MFMAs

    const int abase = (cb * 8 + kb) * 4096 + aoff;
#pragma unroll
    for (int ky = 0; ky < 3; ++ky) {
#pragma unroll
      for (int kx = 0; kx < 3; ++kx) {
        const int t = ky * 3 + kx;
        const ushort_t* wh = Wth + abase + t * 65536;
        const ushort_t* wl = Wtl + abase + t * 65536;
        short8 ah[4], al[4], bh[4], bl[4];
#pragma unroll
        for (int am = 0; am < 4; ++am) {
          ah[am] = *(const short8*)(wh + am * 128);
          al[am] = *(const short8*)(wl + am * 128);
        }
#pragma unroll
        for (int bn = 0; bn < 4; ++bn) {
          int c4 = (kcc * 180 + (wn * 4 + bn + ky) * 18 + (lr + kx)) * 4;
          *(short4v*)&bh[bn]       = *(const short4v*)&XhL[cur][c4];
          *((short4v*)&bh[bn] + 1) = *(const short4v*)&XhL[cur][2880 + c4];
          *(short4v*)&bl[bn]       = *(const short4v*)&XlL[cur][c4];
          *((short4v*)&bl[bn] + 1) = *(const short4v*)&XlL[cur][2880 + c4];
        }
#pragma unroll
        for (int am = 0; am < 4; ++am)
#pragma unroll
          for (int bn = 0; bn < 4; ++bn) {
            acc[am][bn] = __builtin_amdgcn_mfma_f32_16x16x32_bf16(ah[am], bh[bn], acc[am][bn], 0, 0, 0);
            acc[am][bn] = __builtin_amdgcn_mfma_f32_16x16x32_bf16(ah[am], bl[bn], acc[am][bn], 0, 0, 0);
            acc[am][bn] = __builtin_amdgcn_mfma_f32_16x16x32_bf16(al[am], bh[bn], acc[am][bn], 0, 0, 0);
          }
      }
    }
    if (kb < 7) {
      xstore(kb + 1, cur ^ 1, xn);
      __syncthreads();
      cur ^= 1;
    }
  }

  // epilogue: * demod + bias, bounded store
#pragma unroll
  for (int am = 0; am < 4; ++am) {
#pragma unroll
    for (int r = 0; r < 4; ++r) {
      int cog = co0 + wm * 64 + am * 16 + kcc * 4 + r;
      float dm = demod[b * 256 + cog];
      float bv = bias[cog];
#pragma unroll
      for (int bn = 0; bn < 4; ++bn) {
        int oy = y0 + wn * 4 + bn;
        int ox = x0 + lr;
        if (oy < HO_ && ox < HO_)
          out1[((b * 256 + cog) * HO_ + oy) * HO_ + ox] = acc[am][bn][r] * dm + bv;
      }
    }
  }
}

// ---------------- K4: fused FIR up(2x) -> lrelu -> FIR down(2x) ----------------
#define TS 26
#define XR 36
#define UR 62

__global__ __launch_bounds__(256) void k_fir(const float* __restrict__ src,
                                             const float* __restrict__ upf,
                                             const float* __restrict__ dnf,
                                             float* __restrict__ dst) {
  int plane = blockIdx.z;
  int y0 = blockIdx.y * TS, x0 = blockIdx.x * TS;
  int tid = threadIdx.x;

  __shared__ float buf1[UR * 63];
  __shared__ float buf2[UR * 37];
  __shared__ float fu[NT_], fd[NT_];
  if (tid < NT_) { fu[tid] = upf[tid] * 2.f; fd[tid] = dnf[tid]; }

  const float* sp = src + (size_t)plane * HO_ * HO_;
  for (int idx = tid; idx < XR * XR; idx += 256) {
    int r = idx / XR, c = idx % XR;
    int gy = y0 - 5 + r, gx = x0 - 5 + c;
    float v = 0.f;
    if (gy >= 0 && gy < HO_ && gx >= 0 && gx < HO_) v = sp[gy * HO_ + gx];
    buf1[r * 37 + c] = v;
  }
  __syncthreads();

  for (int idx = tid; idx < UR * XR; idx += 256) {
    int u = idx / XR, c = idx % XR;
    int ug = 2 * y0 - 5 + u;
    float a = 0.f;
    if (ug >= 0 && ug < HU_) {
      int base, toff;
      if (ug & 1) { base = (ug - 5) >> 1; toff = 1; }
      else        { base = (ug >> 1) - 3; toff = 0; }
      int lr2 = base - (y0 - 5);
#pragma unroll
      for (int j = 0; j < 6; ++j) a += fu[2 * j + toff] * buf1[(lr2 + j) * 37 + c];
    }
    buf2[u * 37 + c] = a;
  }
  __syncthreads();

  for (int idx = tid; idx < UR * UR; idx += 256) {
    int u = idx / UR, v = idx % UR;
    int ug = 2 * y0 - 5 + u;
    int vg = 2 * x0 - 5 + v;
    float a = 0.f;
    if (ug >= 0 && ug < HU_ && vg >= 0 && vg < HU_) {
      int base, toff;
      if (vg & 1) { base = (vg - 5) >> 1; toff = 1; }
      else        { base = (vg >> 1) - 3; toff = 0; }
      int lc = base - (x0 - 5);
#pragma unroll
      for (int j = 0; j < 6; ++j) a += fu[2 * j + toff] * buf2[u * 37 + lc + j];
      a = (a >= 0.f ? a : 0.2f * a) * 1.41421356237309515f;
      a = fminf(fmaxf(a, -256.f), 256.f);
    }
    buf1[u * 63 + v] = a;
  }
  __syncthreads();

  for (int idx = tid; idx < TS * UR; idx += 256) {
    int y = idx / UR, v = idx % UR;
    float a = 0.f;
#pragma unroll
    for (int t = 0; t < NT_; ++t) a += fd[t] * buf1[(2 * y + t) * 63 + v];
    buf2[y * 63 + v] = a;
  }
  __syncthreads();

  float* dp = dst + (size_t)plane * HO_ * HO_;
  for (int idx = tid; idx < TS * TS; idx += 256) {
    int y = idx / TS, x = idx % TS;
    float a = 0.f;
#pragma unroll
    for (int t = 0; t < NT_; ++t) a += fd[t] * buf2[y * 63 + 2 * x + t];
    dp[(y0 + y) * HO_ + (x0 + x)] = a;
  }
}

// ---------------- launch ----------------
extern "C" void kernel_launch(void* const* d_in, const int* in_sizes, int n_in,
                              void* d_out, int out_size, void* d_ws, size_t ws_size,
                              hipStream_t stream) {
  (void)in_sizes; (void)n_in; (void)out_size; (void)ws_size;
  const float* input  = (const float*)d_in[0];
  const float* style  = (const float*)d_in[1];
  const float* weight = (const float*)d_in[2];
  const float* mw     = (const float*)d_in[3];
  const float* mb     = (const float*)d_in[4];
  const float* bias   = (const float*)d_in[5];
  const float* upf    = (const float*)d_in[6];
  const float* dnf    = (const float*)d_in[7];
  float* out = (float*)d_out;

  float* out1   = (float*)d_ws;                               // [4][256][130][130]
  float* s      = out1 + (size_t)B_ * COUT_ * HO_ * HO_;      // [4][256]
  float* demod  = s + B_ * CIN_;                              // [4][256]
  ushort_t* Wth = (ushort_t*)(demod + B_ * COUT_);            // 589824
  ushort_t* Wtl = Wth + 589824;                               // 589824

  k_mod   <<<256, 256, 0, stream>>>(style, mw, mb, s);
  k_demod <<<256, 256, 0, stream>>>(weight, s, demod);
  k_prep_w<<<2304, 256, 0, stream>>>(weight, Wth, Wtl);
  k_conv_mfma<<<dim3(9, 17, 8), 256, 0, stream>>>(input, Wth, Wtl, s, demod, bias, out1);
  k_fir   <<<dim3(5, 5, B_ * COUT_), 256, 0, stream>>>(out1, upf, dnf, out);
}